// Round 1
// baseline (527.397 us; speedup 1.0000x reference)
//
#include <hip/hip_runtime.h>

// ChaosModulator: per-(b,c) nonlinear recurrence over t.
//   sigma = 3.5*z*(1-z) + 0.5*x_t
//   z'    = 0.5*z + 0.5*0.5*(1+tanh(sigma))   [gamma=0.5]
//         = 0.5*z + 0.5*sigmoid(2*sigma)      (clip is a provable no-op)
//   u_t   = 0.5*x_t + z' - 0.5                 [lam=0.5]
//
// b*c = 16384 independent sequences, t=4096, t-contiguous rows.
// One thread per sequence; 256 blocks x 64 threads = 1 wave per CU.
// Register double-buffer prefetch of 8 float4 (32 t-steps) per stage.

#define SEQ_T 4096
#define PF 8                      // float4s per pipeline stage
#define NBLK (SEQ_T / (PF * 4))   // 128 stages

__device__ __forceinline__ void chaos_step(float& z, float xs, float& us) {
    const float CA = -10.098865286222744f;  // 3.5 * (-2*log2(e))
    const float CB = -1.4426950408889634f;  // 0.5 * (-2*log2(e))
    float p  = CB * xs;                         // off-chain
    float hz = 0.5f * z;                        // parallel path
    float zz = __builtin_fmaf(-z, z, z);        // z - z^2     (chain)
    float s  = __builtin_fmaf(CA, zz, p);       // -2*log2e*sigma
    float e  = exp2f(s);                        // v_exp_f32
    float r  = __builtin_amdgcn_rcpf(e + 1.0f); // sigmoid(2*sigma)
    z = __builtin_fmaf(0.5f, r, hz);            // z' = 0.5z + 0.5*sig
    us = __builtin_fmaf(0.5f, xs, z - 0.5f);    // u  (off-chain)
}

__global__ __launch_bounds__(64, 1)
void ChaosModulator_28922309771717_kernel(const float* __restrict__ x,
                                          const float* __restrict__ z0,
                                          float* __restrict__ u) {
    const int seq = blockIdx.x * 64 + threadIdx.x;      // 0..16383
    const float4* __restrict__ xv = (const float4*)(x + (size_t)seq * SEQ_T);
    float4* __restrict__ uv = (float4*)(u + (size_t)seq * SEQ_T);

    float z = z0[seq];

    float4 buf[PF];
#pragma unroll
    for (int k = 0; k < PF; ++k) buf[k] = xv[k];

    for (int blk = 0; blk < NBLK; ++blk) {
        float4 cur[PF];
#pragma unroll
        for (int k = 0; k < PF; ++k) cur[k] = buf[k];

        if (blk + 1 < NBLK) {
#pragma unroll
            for (int k = 0; k < PF; ++k) buf[k] = xv[(blk + 1) * PF + k];
        }

#pragma unroll
        for (int k = 0; k < PF; ++k) {
            float4 xq = cur[k];
            float4 uq;
            chaos_step(z, xq.x, uq.x);
            chaos_step(z, xq.y, uq.y);
            chaos_step(z, xq.z, uq.z);
            chaos_step(z, xq.w, uq.w);
            uv[blk * PF + k] = uq;
        }
    }
}

extern "C" void kernel_launch(void* const* d_in, const int* in_sizes, int n_in,
                              void* d_out, int out_size, void* d_ws, size_t ws_size,
                              hipStream_t stream) {
    const float* x  = (const float*)d_in[0];   // (32, 512, 4096)
    const float* z0 = (const float*)d_in[1];   // (32, 512)
    float* u = (float*)d_out;                  // (32, 512, 4096)

    const int n_seq = in_sizes[1];             // 16384
    dim3 grid(n_seq / 64), block(64);
    ChaosModulator_28922309771717_kernel<<<grid, block, 0, stream>>>(x, z0, u);
}